// Round 4
// baseline (338.145 us; speedup 1.0000x reference)
//
#include <hip/hip_runtime.h>

typedef unsigned short u16;
typedef short short8 __attribute__((ext_vector_type(8)));
typedef float floatx4 __attribute__((ext_vector_type(4)));

#define NE 800000
#define NNODES 50000

#define LDS_FENCE() __asm__ volatile("s_waitcnt lgkmcnt(0)" ::: "memory")

__device__ __forceinline__ u16 f2bf(float f) {
    union { float f; unsigned int i; } v; v.f = f;
    return (u16)((v.i + 0x7fffu + ((v.i >> 16) & 1u)) >> 16);
}
__device__ __forceinline__ float bf2f(u16 u) {
    union { unsigned int i; float f; } v; v.i = ((unsigned int)u) << 16; return v.f;
}
// load 8 consecutive fp32, round to bf16, return packed short8
__device__ __forceinline__ short8 ld8_bf(const float* __restrict__ p) {
    const float4 a = *(const float4*)p;
    const float4 b = *(const float4*)(p + 4);
    short8 o;
    o[0] = (short)f2bf(a.x); o[1] = (short)f2bf(a.y);
    o[2] = (short)f2bf(a.z); o[3] = (short)f2bf(a.w);
    o[4] = (short)f2bf(b.x); o[5] = (short)f2bf(b.y);
    o[6] = (short)f2bf(b.z); o[7] = (short)f2bf(b.w);
    return o;
}

#define MFMA16(a, b, c) __builtin_amdgcn_mfma_f32_16x16x32_bf16(a, b, c, 0, 0, 0)

// ---------------------------------------------------------------------------
// Edge kernel: per 16-edge tile (one wave):
//   A1[16x96] = [bf16(x[src]) (64) | bf16(edge_feat) (16) | zero pad (16)]
//   h   = relu(A1 @ W1 + b1)      (MFMA K=96, W1 zero-padded k>=80)
//   msg = h @ W2 + b2             (h via LDS C->A layout round trip)
//   atomicAdd msg into agg[dst] (fp32), atomicAdd 1 into cnt[dst]
// ---------------------------------------------------------------------------
__global__ __launch_bounds__(256) void edge_kernel(
    const float* __restrict__ x, const int* __restrict__ ei,
    const float* __restrict__ ef, const float* __restrict__ w1,
    const float* __restrict__ b1, const float* __restrict__ w2,
    const float* __restrict__ b2, float* __restrict__ agg,
    float* __restrict__ cnt)
{
    constexpr int S1 = 104;  // A1 row stride (bf16) — pad 96->104 (2-way bank alias only)
    constexpr int S2 = 72;   // h row stride — pad 64->72
    __shared__ u16 A1[4][16 * S1];
    __shared__ u16 Hs[4][16 * S2];
    __shared__ int Ds[4][16];

    const int wid  = threadIdx.x >> 6;
    const int lane = threadIdx.x & 63;
    const int q    = lane >> 4;   // quad (16-lane group)
    const int c    = lane & 15;   // col within quad

    // B-fragments, register resident. B[k][n]: n = 16*nn + c, k = 32*kk + q*8 + j
    short8 w1f[3][4], w2f[2][4];
    #pragma unroll
    for (int kk = 0; kk < 3; ++kk)
        #pragma unroll
        for (int nn = 0; nn < 4; ++nn)
            #pragma unroll
            for (int j = 0; j < 8; ++j) {
                const int k = kk * 32 + q * 8 + j;
                w1f[kk][nn][j] = (k < 80) ? (short)f2bf(w1[k * 64 + nn * 16 + c]) : (short)0;
            }
    #pragma unroll
    for (int kk = 0; kk < 2; ++kk)
        #pragma unroll
        for (int nn = 0; nn < 4; ++nn)
            #pragma unroll
            for (int j = 0; j < 8; ++j) {
                const int k = kk * 32 + q * 8 + j;
                w2f[kk][nn][j] = (short)f2bf(w2[k * 64 + nn * 16 + c]);
            }
    float b1v[4], b2v[4];
    #pragma unroll
    for (int nn = 0; nn < 4; ++nn) {
        b1v[nn] = b1[nn * 16 + c];
        b2v[nn] = b2[nn * 16 + c];
    }

    const floatx4 zero = {0.f, 0.f, 0.f, 0.f};
    const int ntile = NE / 16;  // 50000 exactly

    for (int t = blockIdx.x * 4 + wid; t < ntile; t += gridDim.x * 4) {
        const int e0 = t * 16;
        const int m = c;        // row this lane stages
        const int e = e0 + m;
        u16* arow = &A1[wid][m * S1];

        const int src = ei[e];
        const float* xp = x + (size_t)src * 64 + q * 16;
        *(short8*)&arow[q * 16]     = ld8_bf(xp);
        *(short8*)&arow[q * 16 + 8] = ld8_bf(xp + 8);
        if (q == 0) {
            const float* ep = ef + (size_t)e * 16;
            *(short8*)&arow[64] = ld8_bf(ep);
            *(short8*)&arow[72] = ld8_bf(ep + 8);
        } else if (q == 1) {
            const short8 z8 = {0, 0, 0, 0, 0, 0, 0, 0};
            *(short8*)&arow[80] = z8;
            *(short8*)&arow[88] = z8;
        } else if (q == 2) {
            const int d = ei[NE + e];
            Ds[wid][m] = d;
            atomicAdd(&cnt[d], 1.0f);
        }
        LDS_FENCE();

        // A fragments: A[m = c][k = 32*kk + q*8 + j]  (wave-private LDS)
        short8 a1k[3];
        #pragma unroll
        for (int kk = 0; kk < 3; ++kk)
            a1k[kk] = *(const short8*)&A1[wid][c * S1 + kk * 32 + q * 8];

        // GEMM1 + bias + relu -> Hs (bf16, row-major => A-layout-ready)
        #pragma unroll
        for (int nn = 0; nn < 4; ++nn) {
            floatx4 acc = MFMA16(a1k[0], w1f[0][nn], zero);
            acc = MFMA16(a1k[1], w1f[1][nn], acc);
            acc = MFMA16(a1k[2], w1f[2][nn], acc);
            #pragma unroll
            for (int r = 0; r < 4; ++r) {
                const float h = fmaxf(acc[r] + b1v[nn], 0.f);
                Hs[wid][(q * 4 + r) * S2 + nn * 16 + c] = f2bf(h);
            }
        }
        LDS_FENCE();

        short8 a2k[2];
        #pragma unroll
        for (int kk = 0; kk < 2; ++kk)
            a2k[kk] = *(const short8*)&Hs[wid][c * S2 + kk * 32 + q * 8];

        floatx4 msg[4];
        #pragma unroll
        for (int nn = 0; nn < 4; ++nn) {
            msg[nn] = MFMA16(a2k[0], w2f[0][nn], zero);
            msg[nn] = MFMA16(a2k[1], w2f[1][nn], msg[nn]);
        }

        // scatter: element (row=q*4+r, col=nn*16+c)
        #pragma unroll
        for (int r = 0; r < 4; ++r) {
            const int d = Ds[wid][q * 4 + r];
            float* base = agg + (size_t)d * 64 + c;
            #pragma unroll
            for (int nn = 0; nn < 4; ++nn)
                atomicAdd(base + nn * 16, msg[nn][r] + b2v[nn]);
        }
    }
}

// ---------------------------------------------------------------------------
// Node kernel: per 16-node tile (one wave):
//   cat[16x128] = [bf16(x) | bf16(agg/(cnt+1e-8))]
//   upd = relu(cat @ W3 + b3); y = upd + x; LayerNorm(y)*gamma+beta -> fp32 out
// ---------------------------------------------------------------------------
__global__ __launch_bounds__(256) void node_kernel(
    const float* __restrict__ x, const float* __restrict__ w3,
    const float* __restrict__ b3, const float* __restrict__ g,
    const float* __restrict__ bb, const float* __restrict__ agg,
    const float* __restrict__ cnt, float* __restrict__ out)
{
    constexpr int S3 = 136;  // 128 + 8 pad
    __shared__ u16 Cs[4][16 * S3];

    const int wid  = threadIdx.x >> 6;
    const int lane = threadIdx.x & 63;
    const int q    = lane >> 4;
    const int c    = lane & 15;

    short8 w3f[4][4];
    #pragma unroll
    for (int kk = 0; kk < 4; ++kk)
        #pragma unroll
        for (int nn = 0; nn < 4; ++nn)
            #pragma unroll
            for (int j = 0; j < 8; ++j) {
                const int k = kk * 32 + q * 8 + j;
                w3f[kk][nn][j] = (short)f2bf(w3[k * 64 + nn * 16 + c]);
            }
    float b3v[4], gv[4], bv[4];
    #pragma unroll
    for (int nn = 0; nn < 4; ++nn) {
        b3v[nn] = b3[nn * 16 + c];
        gv[nn]  = g[nn * 16 + c];
        bv[nn]  = bb[nn * 16 + c];
    }

    const floatx4 zero = {0.f, 0.f, 0.f, 0.f};
    const int ntile = NNODES / 16;  // 3125 exactly

    for (int t = blockIdx.x * 4 + wid; t < ntile; t += gridDim.x * 4) {
        const int n0 = t * 16;
        const int m = c;
        const int node = n0 + m;
        u16* crow = &Cs[wid][m * S3];

        if (q < 2) {
            const float* xp = x + (size_t)node * 64 + q * 32;
            #pragma unroll
            for (int gi = 0; gi < 4; ++gi)
                *(short8*)&crow[q * 32 + gi * 8] = ld8_bf(xp + gi * 8);
        } else {
            const int p = q - 2;
            const float inv = 1.0f / (cnt[node] + 1e-8f);
            const float* ap = agg + (size_t)node * 64 + p * 32;
            #pragma unroll
            for (int gi = 0; gi < 4; ++gi) {
                const float4 v0 = *(const float4*)(ap + gi * 8);
                const float4 v1 = *(const float4*)(ap + gi * 8 + 4);
                short8 o;
                o[0] = (short)f2bf(v0.x * inv);
                o[1] = (short)f2bf(v0.y * inv);
                o[2] = (short)f2bf(v0.z * inv);
                o[3] = (short)f2bf(v0.w * inv);
                o[4] = (short)f2bf(v1.x * inv);
                o[5] = (short)f2bf(v1.y * inv);
                o[6] = (short)f2bf(v1.z * inv);
                o[7] = (short)f2bf(v1.w * inv);
                *(short8*)&crow[64 + p * 32 + gi * 8] = o;
            }
        }
        LDS_FENCE();

        short8 af[4];
        #pragma unroll
        for (int kk = 0; kk < 4; ++kk)
            af[kk] = *(const short8*)&Cs[wid][c * S3 + kk * 32 + q * 8];

        float y[4][4];
        float s[4]  = {0.f, 0.f, 0.f, 0.f};
        float ss[4] = {0.f, 0.f, 0.f, 0.f};
        #pragma unroll
        for (int nn = 0; nn < 4; ++nn) {
            floatx4 acc = MFMA16(af[0], w3f[0][nn], zero);
            acc = MFMA16(af[1], w3f[1][nn], acc);
            acc = MFMA16(af[2], w3f[2][nn], acc);
            acc = MFMA16(af[3], w3f[3][nn], acc);
            #pragma unroll
            for (int r = 0; r < 4; ++r) {
                const float upd = fmaxf(acc[r] + b3v[nn], 0.f);
                const float xv = bf2f(Cs[wid][(q * 4 + r) * S3 + nn * 16 + c]);
                const float yy = upd + xv;
                y[r][nn] = yy;
                s[r] += yy;
                ss[r] += yy * yy;
            }
        }

        // LayerNorm per row: row q*4+r lives in this quad's 16 lanes x 4 regs
        #pragma unroll
        for (int r = 0; r < 4; ++r) {
            float sr = s[r], sq = ss[r];
            #pragma unroll
            for (int off = 1; off < 16; off <<= 1) {
                sr += __shfl_xor(sr, off);
                sq += __shfl_xor(sq, off);
            }
            const float mu  = sr * (1.0f / 64.0f);
            const float var = sq * (1.0f / 64.0f) - mu * mu;
            const float rs  = rsqrtf(var + 1e-5f);
            float* op = out + (size_t)(n0 + q * 4 + r) * 64 + c;
            #pragma unroll
            for (int nn = 0; nn < 4; ++nn)
                op[nn * 16] = (y[r][nn] - mu) * rs * gv[nn] + bv[nn];
        }
    }
}

extern "C" void kernel_launch(void* const* d_in, const int* in_sizes, int n_in,
                              void* d_out, int out_size, void* d_ws, size_t ws_size,
                              hipStream_t stream) {
    const float* x   = (const float*)d_in[0];
    const int*   ei  = (const int*)d_in[1];
    const float* ef  = (const float*)d_in[2];
    const float* w1  = (const float*)d_in[3];
    const float* b1  = (const float*)d_in[4];
    const float* w2  = (const float*)d_in[5];
    const float* b2  = (const float*)d_in[6];
    const float* w3  = (const float*)d_in[7];
    const float* b3  = (const float*)d_in[8];
    const float* g   = (const float*)d_in[9];
    const float* bb  = (const float*)d_in[10];

    float* agg = (float*)d_ws;
    float* cnt = agg + (size_t)NNODES * 64;

    hipMemsetAsync(d_ws, 0, (size_t)(NNODES * 64 + NNODES) * sizeof(float), stream);
    edge_kernel<<<1024, 256, 0, stream>>>(x, ei, ef, w1, b1, w2, b2, agg, cnt);
    node_kernel<<<392, 256, 0, stream>>>(x, w3, b3, g, bb, agg, cnt, (float*)d_out);
}